// Round 7
// baseline (469.415 us; speedup 1.0000x reference)
//
#include <hip/hip_runtime.h>

// Brute N^2 neighborlist (upper-triangular pairs), N=6000, P=17,997,000.
// Output layout (flat f32): [0,P) i | [P,2P) j | [2P,3P) d | [3P,6P) r_xyz.
//
// R7: the output is ~99.95% the constant background (-1,-1,0,0,0,0) — only
// ~9.4K pairs are in-cutoff (5.2e-4 density). R1-R6 showed our own store
// stream tops out at ~4.3 TB/s while rocclr fillBuffer hits 6.06 TB/s on
// this buffer. So: delegate the background to two runtime memset nodes
// (i/j = -1.0f via hipMemsetD32Async, d/r = 0 via hipMemsetAsync), then run
// a compute-only kernel that scatters just the in-cutoff entries (~1.6% of
// waves take the store path). PBC wrap replicates numpy remainder bitwise
// (Sterbenz-exact branches, |r| < box, box > 0); explicit _rn intrinsics
// forbid contraction so the d<=0.5 mask cannot flip vs numpy.

constexpr int NPART  = 6000;
constexpr int NPAIRS = 17997000;     // N*(N-1)/2
constexpr float CUT  = 0.5f;
constexpr int TPB = 256;

__device__ __forceinline__ int row_start(int i) {
    // pairs before row i: S(i) = i*(N-1) - i*(i-1)/2  (fits int32)
    return i * (NPART - 1) - (i * (i - 1)) / 2;
}

// numpy remainder(r+h, b) - h for |r| < b, b > 0, h = b/2 — bitwise-exact.
__device__ __forceinline__ float pbc_wrap(float r, float b, float h) {
    float v = __fadd_rn(r, h);
    if (v >= b)       v = __fsub_rn(v, b);
    else if (v < 0.f) v = __fadd_rn(v, b);
    return __fsub_rn(v, h);
}

__global__ __launch_bounds__(TPB) void nbl_scatter_kernel(
    const float* __restrict__ pos,     // [N,3]
    const float* __restrict__ boxv,    // [3,3]
    const int*  __restrict__ is_per,
    float* __restrict__ out)
{
    const int p = blockIdx.x * TPB + threadIdx.x;   // one pair per thread
    if (p >= NPAIRS) return;

    // invert triangular index: exact int32 discriminant (>= 9, never
    // negative -> no NaN tail), fp32 sqrt estimate + <=2-step fixup.
    int disc_i = 143976001 - 8 * p;                 // (2N-1)^2 - 8p
    float sq = sqrtf((float)disc_i);
    int i = (int)((11999.0f - sq) * 0.5f);
    if (i < 0) i = 0;
    if (i > NPART - 2) i = NPART - 2;
    while (i < NPART - 2 && row_start(i + 1) <= p) ++i;
    while (i > 0 && row_start(i) > p) --i;
    const int j = i + 1 + (p - row_start(i));

    float rx = __fsub_rn(pos[3 * i + 0], pos[3 * j + 0]);
    float ry = __fsub_rn(pos[3 * i + 1], pos[3 * j + 1]);
    float rz = __fsub_rn(pos[3 * i + 2], pos[3 * j + 2]);

    if (*is_per != 0) {
        const float bx = boxv[0], by = boxv[4], bz = boxv[8];
        rx = pbc_wrap(rx, bx, __fmul_rn(bx, 0.5f));
        ry = pbc_wrap(ry, by, __fmul_rn(by, 0.5f));
        rz = pbc_wrap(rz, bz, __fmul_rn(bz, 0.5f));
    }

    float s = __fadd_rn(__fadd_rn(__fmul_rn(rx, rx), __fmul_rn(ry, ry)),
                        __fmul_rn(rz, rz));
    float d = __fsqrt_rn(s);

    if (d <= CUT) {                                 // ~5.2e-4 of threads
        out[p]              = (float)i;
        out[NPAIRS + p]     = (float)j;
        out[2 * NPAIRS + p] = d;
        float* rb = out + 3 * NPAIRS + 3 * p;
        rb[0] = rx; rb[1] = ry; rb[2] = rz;
    }
}

extern "C" void kernel_launch(void* const* d_in, const int* in_sizes, int n_in,
                              void* d_out, int out_size, void* d_ws, size_t ws_size,
                              hipStream_t stream) {
    const float* pos    = (const float*)d_in[0];
    const float* boxv   = (const float*)d_in[1];
    const int*   is_per = (const int*)d_in[2];
    float* out = (float*)d_out;

    // Background: i/j streams = -1.0f (0xBF800000), d/r streams = 0.
    hipMemsetD32Async((hipDeviceptr_t)out, (int)0xBF800000,
                      (size_t)2 * NPAIRS, stream);
    hipMemsetAsync(out + (size_t)2 * NPAIRS, 0,
                   (size_t)4 * NPAIRS * sizeof(float), stream);

    const int grid = (NPAIRS + TPB - 1) / TPB;      // 70,301
    nbl_scatter_kernel<<<grid, TPB, 0, stream>>>(pos, boxv, is_per, out);
}